// Round 5
// baseline (370.950 us; speedup 1.0000x reference)
//
#include <hip/hip_runtime.h>
#include <hip/hip_fp16.h>
#include <cmath>

#define NN 50000
#define NE 800000
#define PADF 96  // fallback local sort cap; P(Poisson(16) > 96) ~ 1e-40
#define NBIN 196     // coarse bins: dst>>8 (dst<50000 -> bin<196)
#define NBLK 391     // edge chunks of 2048 (391*2048 = 800768 >= NE)
#define FCAP 6144    // fine-bucket LDS cap (mean 4082, sigma~64; 6144 = +32 sigma)
// int32-overflow boundary of the reference's argsort key (jax x64 disabled):
// key = dst*50000+src wraps for dst>42949, or dst==42949 && src>=33648.
// VERIFIED (prev session): jax order = rotate(bucket, s0), norm indexed by UNROTATED j
// (rnrm at sorted position idx pairs with j = idx - s0 mod NE, src = RAW src array).
#define DST_HI 42949
#define SRC_CUT 33648
// R4 lesson: every device-scope atomic writes a ~32B HBM sector (1.6M atomics == 51.4MB
// measured). This version has ZERO device-scope atomics: MSD bucket sort with LDS-only
// atomics (keys (dst,src) unique -> stability irrelevant -> unordered LDS ranks OK).

__device__ __forceinline__ unsigned short f2h(float f) {  // RNE fp32 -> fp16 (11-bit mantissa)
  __half h = __float2half_rn(f);
  return *reinterpret_cast<unsigned short*>(&h);
}

// ---- k_aux: [0,196) rptr+dout | [196,276) Weff | [276,667) X->fp16 | [667,1058) coarse hist.
// Hist: per-chunk LDS histogram of dst>>8, written to H[bin*NBLK+chunk] (coalesced-ish).
__global__ __launch_bounds__(256) void k_aux(const float* __restrict__ X, const int* __restrict__ src,
                                             const int* __restrict__ dst, const float* __restrict__ ew,
                                             int* __restrict__ H,
                                             int* __restrict__ rptr, float* __restrict__ dout,
                                             const float* __restrict__ Wz, const float* __restrict__ Wh,
                                             float* __restrict__ Weff, unsigned short* __restrict__ Xh) {
  __shared__ int hh[256];
  int bid = blockIdx.x;
  int t = threadIdx.x;
  if (bid >= 667) {
    int h = bid - 667;                       // chunk id in [0, NBLK)
    hh[t] = 0;
    __syncthreads();
#pragma unroll
    for (int r = 0; r < 8; ++r) {
      int e = h * 2048 + r * 256 + t;
      if (e < NE) atomicAdd(&hh[dst[e] >> 8], 1);   // LDS atomic only
    }
    __syncthreads();
    if (t < NBIN) H[t * NBLK + h] = hh[t];
  } else if (bid < 196) {
    int i = bid * 256 + t;
    if (i >= NN) return;
    int lo = 0, hi = NE;
    while (lo < hi) { int m = (lo + hi) >> 1; if (src[m] < i) lo = m + 1; else hi = m; }
    int lo2 = lo, hi2 = NE;
    while (lo2 < hi2) { int m = (lo2 + hi2) >> 1; if (src[m] < i + 1) lo2 = m + 1; else hi2 = m; }
    rptr[i] = lo;
    if (i == NN - 1) rptr[NN] = lo2;
    float a = 0.f;
    for (int p = lo; p < lo2; ++p) a += ew[p];
    dout[i] = a;
  } else if (bid < 276) {
    int idx = (bid - 196) * 256 + t;  // 80*256 == 160*128 exactly
    int kk = idx >> 7, f = idx & 127;
    int blk = kk >> 5, c = kk & 31;
    const float* W = (f < 64) ? Wz : Wh;
    int fl = f & 63;
    float v;
    if (blk == 0)      v = W[c * 64 + fl] + W[18432 + c * 64 + fl];
    else if (blk == 1) v = W[6144 + c * 64 + fl];
    else if (blk == 2) v = W[18432 + 6144 + c * 64 + fl];
    else if (blk == 3) v = W[2 * 6144 + c * 64 + fl];
    else               v = W[18432 + 2 * 6144 + c * 64 + fl];
    Weff[idx] = v;
  } else {
    // X -> fp16 copy: 1.6M elems, 16/thread
    int tt = (bid - 276) * 256 + t;
    int base = tt * 16;
    if (base >= NN * 32) return;
#pragma unroll
    for (int q = 0; q < 2; ++q) {
      const float4 a = *(const float4*)&X[base + q * 8];
      const float4 b = *(const float4*)&X[base + q * 8 + 4];
      ushort4 o1 = make_ushort4(f2h(a.x), f2h(a.y), f2h(a.z), f2h(a.w));
      ushort4 o2 = make_ushort4(f2h(b.x), f2h(b.y), f2h(b.z), f2h(b.w));
      *(ushort4*)&Xh[base + q * 8] = o1;
      *(ushort4*)&Xh[base + q * 8 + 4] = o2;
    }
  }
}

// ---- k_scan: in-place exclusive scan of H[NBIN*NBLK] (bin-major), one block. ----
__global__ __launch_bounds__(1024) void k_scan(int* __restrict__ H) {
  __shared__ int tmp[1024];
  const int total = NBIN * NBLK;           // 76636
  const int per = 75;                      // ceil(76636/1024)
  int t = threadIdx.x;
  int lo = t * per, hi = lo + per; if (hi > total) hi = total;
  int s = 0;
  for (int i = lo; i < hi; ++i) s += H[i];
  tmp[t] = s;
  __syncthreads();
  for (int off = 1; off < 1024; off <<= 1) {
    int v = (t >= (unsigned)off) ? tmp[t - off] : 0;
    __syncthreads();
    tmp[t] += v;
    __syncthreads();
  }
  int run = tmp[t] - s;                    // exclusive base for this thread's range
  for (int i = lo; i < hi; ++i) { int v = H[i]; H[i] = run; run += v; }
}

// ---- k_part: coarse partition by dst>>8. pos = P[bin*NBLK+chunk] + LDS rank (unordered,
// fine: keys unique). Packed u64 {dstLow:8 @48, src:16 @24, e:24}. Per-(bin,chunk) runs are
// contiguous (~10 items) -> lines complete in L2 before writeback. ----
__global__ __launch_bounds__(256) void k_part(const int* __restrict__ src, const int* __restrict__ dst,
                                              const int* __restrict__ P,
                                              unsigned long long* __restrict__ cmp64) {
  __shared__ int loc[NBIN];
  int h = blockIdx.x;
  int t = threadIdx.x;
  if (t < NBIN) loc[t] = 0;
  __syncthreads();
#pragma unroll
  for (int r = 0; r < 8; ++r) {
    int e = h * 2048 + r * 256 + t;
    if (e < NE) {
      int d = dst[e];
      int bin = d >> 8;
      int rk = atomicAdd(&loc[bin], 1);               // LDS atomic
      int pos = P[bin * NBLK + h] + rk;
      cmp64[pos] = ((unsigned long long)(d & 255) << 48) |
                   ((unsigned long long)src[e] << 24) | (unsigned long long)e;
    }
  }
}

// ---- k_fine: one block per coarse bucket (256 dst values). In-LDS counting sort by dstLow
// (unordered ranks), then coalesced emit of cmp{e,src}, sp, and din (segmented ew sum). ----
__global__ __launch_bounds__(1024) void k_fine(const int* __restrict__ P, const float* __restrict__ ew,
                                               const unsigned long long* __restrict__ cmp64,
                                               int2* __restrict__ cmp, int* __restrict__ sp,
                                               float* __restrict__ din) {
  __shared__ unsigned long long a1[FCAP], a2[FCAP];
  __shared__ int fh[256], fcnt[256], fo[257];
  int cb = blockIdx.x;
  int t = threadIdx.x;
  int base = P[cb * NBLK];
  int end = (cb == NBIN - 1) ? NE : P[(cb + 1) * NBLK];
  int m = end - base;
  if (m > FCAP) m = FCAP;                 // paranoia guard (P ~ 0)
  if (t < 256) { fh[t] = 0; fcnt[t] = 0; }
  __syncthreads();
  for (int i = t; i < m; i += 1024) {
    unsigned long long it = cmp64[base + i];
    a1[i] = it;
    atomicAdd(&fh[(int)(it >> 48)], 1);
  }
  __syncthreads();
  // exclusive scan of fh[256] by wave 0 (no barriers needed inside)
  if (t < 64) {
    int v0 = fh[t * 4], v1 = fh[t * 4 + 1], v2 = fh[t * 4 + 2], v3 = fh[t * 4 + 3];
    int s1 = v0 + v1, s2 = s1 + v2, tot = s2 + v3;
    int run = tot;
    for (int off = 1; off < 64; off <<= 1) {
      int v = __shfl_up(run, off, 64);
      if (t >= off) run += v;
    }
    int excl = run - tot;
    fo[t * 4] = excl; fo[t * 4 + 1] = excl + v0; fo[t * 4 + 2] = excl + s1; fo[t * 4 + 3] = excl + s2;
    if (t == 63) fo[256] = excl + tot;    // == m
  }
  __syncthreads();
  // unordered stable-free scatter into a2 (keys unique -> k_sortw's bitonic fixes order)
  for (int i = t; i < m; i += 1024) {
    unsigned long long it = a1[i];
    int b = (int)(it >> 48);
    int p2 = fo[b] + atomicAdd(&fcnt[b], 1);
    a2[p2] = it;
  }
  __syncthreads();
  // emit cmp {e, src} coalesced
  for (int i = t; i < m; i += 1024) {
    unsigned long long it = a2[i];
    cmp[base + i] = make_int2((int)(it & 0xFFFFFF), (int)((it >> 24) & 0xFFFF));
  }
  // emit sp (d <= NN covers sp[NN] = NE automatically at cb==195, t==80)
  if (t < 257) {
    int d = cb * 256 + t;
    if (d <= NN && t < 256) sp[d] = base + fo[t];
    else if (d == NN + 0 && t == 256) {}
  }
  {
    int d = cb * 256 + t;
    if (t < 257 && d == NN) sp[NN] = base + fo[t];   // t may be 80 at cb==195 (fo[80]==m)
  }
  // din: 4 lanes per dst, segmented sum of ew over [fo[nd], fo[nd+1])
  int nd = t >> 2, ln = t & 3;
  int d = cb * 256 + nd;
  if (d < NN) {
    float s = 0.f;
    int e0 = fo[nd], e1 = fo[nd + 1];
    for (int i = e0 + ln; i < e1; i += 4) s += ew[(int)(a2[i] & 0xFFFFFF)];
    s += __shfl_down(s, 2, 4);
    s += __shfl_down(s, 1, 4);
    if (ln == 0) din[d] = s;
  }
}

// ---- wave-per-dst: coalesced compact-bucket read -> 64b-key bitonic sort -> cnf
//      (coalesced) + cnr (the ONE scatter). s0 computed inline per block from sp. ----
__global__ __launch_bounds__(256) void k_sortw(const int* __restrict__ sp, const int2* __restrict__ cmp,
                                               const int* __restrict__ rawsrc,
                                               const float* __restrict__ dout, const float* __restrict__ din,
                                               int2* __restrict__ cnf, int2* __restrict__ cnr) {
  __shared__ int s0s;
  {
    int t = threadIdx.x;
    if (t < 64) {
      int b0h = sp[DST_HI];
      int nh = sp[DST_HI + 1] - b0h;
      int c = 0;
      for (int i = t; i < nh; i += 64) c += (cmp[b0h + i].y < SRC_CUT);
      c += __shfl_xor(c, 32, 64); c += __shfl_xor(c, 16, 64); c += __shfl_xor(c, 8, 64);
      c += __shfl_xor(c, 4, 64);  c += __shfl_xor(c, 2, 64);  c += __shfl_xor(c, 1, 64);
      if (t == 0) s0s = b0h + c;
    }
  }
  __syncthreads();
  int wv = (blockIdx.x * 256 + threadIdx.x) >> 6;
  int lane = threadIdx.x & 63;
  if (wv >= NN) return;
  int b0 = sp[wv], b1 = sp[wv + 1];
  int n = b1 - b0;
  int s0 = s0s;
  if (n > 64) {  // 64<n<=96 safety path (never hit at Poisson(16))
    if (lane == 0) {
      int es[PADF], ss[PADF];
      int nn = n > PADF ? PADF : n;
      for (int i = 0; i < nn; ++i) { int2 pe = cmp[b0 + i]; es[i] = pe.x; ss[i] = pe.y; }
      for (int i = 1; i < nn; ++i) {
        int ve = es[i], vs = ss[i]; int j = i - 1;
        while (j >= 0 && es[j] > ve) { es[j + 1] = es[j]; ss[j + 1] = ss[j]; --j; }
        es[j + 1] = ve; ss[j + 1] = vs;
      }
      for (int i = 0; i < nn; ++i) {
        int vs = ss[i];
        cnf[b0 + i] = make_int2(vs, __float_as_int(1.0f / dout[vs]));
        int j = b0 + i - s0; if (j < 0) j += NE;
        cnr[es[i]] = make_int2(wv, __float_as_int(1.0f / din[rawsrc[j]]));
      }
    }
    return;
  }
  unsigned long long k = ~0ULL;
  if (lane < n) {
    int2 pe = cmp[b0 + lane];   // coalesced contiguous read
    k = ((unsigned long long)(unsigned)pe.x << 32) | (unsigned)pe.y;  // key=e, payload=src
  }
  if (n > 1) {
#pragma unroll
    for (int kk = 2; kk <= 64; kk <<= 1) {
#pragma unroll
      for (int j = kk >> 1; j > 0; j >>= 1) {
        unsigned long long o = __shfl_xor(k, j, 64);
        bool lower = (lane & j) == 0;
        bool asc = (lane & kk) == 0;
        bool keepmin = (lower == asc);
        if (keepmin ? (o < k) : (o > k)) k = o;
      }
    }
  }
  if (lane < n) {
    int ve = (int)(k >> 32);
    int vs = (int)(k & 0xffffffffu);
    cnf[b0 + lane] = make_int2(vs, __float_as_int(1.0f / dout[vs]));   // coalesced
    int j = b0 + lane - s0; if (j < 0) j += NE;
    cnr[ve] = make_int2(wv, __float_as_int(1.0f / din[rawsrc[j]]));    // the one scatter
  }
}

// ---- fused pair of gather props, FP16 gather operand (1 line/row vs 2; Xh fits XCD L2;
//      11-bit mantissa: ~8x less rounding than the failed bf16 — lesson R13):
//      accumulate fp32, out fp32 (+ optional fp16 copy for the next prop level). ----
__global__ __launch_bounds__(256) void k_prop2(const unsigned short* __restrict__ inA, const int* __restrict__ rpA,
                                               const int2* __restrict__ cnA, float* __restrict__ outA,
                                               unsigned short* __restrict__ outAh,
                                               const unsigned short* __restrict__ inB, const int* __restrict__ rpB,
                                               const int2* __restrict__ cnB, float* __restrict__ outB,
                                               unsigned short* __restrict__ outBh,
                                               const float* __restrict__ sub, float mul) {
  int t = blockIdx.x * 256 + threadIdx.x;
  const int half = NN * 8;
  const unsigned short* in; const int* rp; const int2* cn; float* out; unsigned short* outh;
  if (t < half) { in = inA; rp = rpA; cn = cnA; out = outA; outh = outAh; }
  else          { in = inB; rp = rpB; cn = cnB; out = outB; outh = outBh; t -= half; }
  int r = t >> 3;
  if (r >= NN) return;
  int lane8 = t & 7;
  int c4 = lane8 * 4;
  int b = rp[r], e2 = rp[r + 1];
  float a0[4] = {0.f, 0.f, 0.f, 0.f}, a1[4] = {0.f, 0.f, 0.f, 0.f};
  int p = b;
#define GATH(cc, ww) { \
    uint2 bv = *(const uint2*)&in[(cc) * 32 + c4]; \
    float2 f01 = __half22float2(*(const __half2*)&bv.x); \
    float2 f23 = __half22float2(*(const __half2*)&bv.y); \
    float* a = (jj & 1) ? a1 : a0; \
    a[0] += (ww) * f01.x; a[1] += (ww) * f01.y; \
    a[2] += (ww) * f23.x; a[3] += (ww) * f23.y; }
  for (; p + 16 <= e2; p += 16) {
    int2 u = cn[p + lane8];              // both chunk-loads in flight before any gather
    int2 v = cn[p + 8 + lane8];
#pragma unroll
    for (int jj = 0; jj < 8; ++jj) {
      int col = __shfl(u.x, jj, 8);
      float w = __int_as_float(__shfl(u.y, jj, 8));
      GATH(col, w)
    }
#pragma unroll
    for (int jj = 0; jj < 8; ++jj) {
      int col = __shfl(v.x, jj, 8);
      float w = __int_as_float(__shfl(v.y, jj, 8));
      GATH(col, w)
    }
  }
  for (; p + 8 <= e2; p += 8) {
    int2 u = cn[p + lane8];
#pragma unroll
    for (int jj = 0; jj < 8; ++jj) {
      int col = __shfl(u.x, jj, 8);
      float w = __int_as_float(__shfl(u.y, jj, 8));
      GATH(col, w)
    }
  }
  for (int jj = 0; p < e2; ++p) {
    int2 c1 = cn[p];
    float w = __int_as_float(c1.y);
    GATH(c1.x, w)
  }
#undef GATH
  float ax = a0[0] + a1[0], ay = a0[1] + a1[1], az = a0[2] + a1[2], aw = a0[3] + a1[3];
  float4 o;
  if (sub) {
    const float4 s = *(const float4*)&sub[r * 32 + c4];
    o.x = mul * ax - s.x; o.y = mul * ay - s.y; o.z = mul * az - s.z; o.w = mul * aw - s.w;
  } else {
    o.x = ax; o.y = ay; o.z = az; o.w = aw;
  }
  *(float4*)&out[r * 32 + c4] = o;
  if (outh) {
    ushort4 oh = make_ushort4(f2h(o.x), f2h(o.y), f2h(o.z), f2h(o.w));
    *(ushort4*)&outh[r * 32 + c4] = oh;
  }
}

// ---- register-blocked GEMM + GRU epilogue: 64x128 tile, K-chunk 32 (25.6 KB LDS) ----
__global__ __launch_bounds__(256) void k_gemm(const float* __restrict__ X, const float* __restrict__ T1o,
                                              const float* __restrict__ T1i, const float* __restrict__ T2o,
                                              const float* __restrict__ T2i,
                                              const float* __restrict__ Weff,
                                              const float* __restrict__ bz, const float* __restrict__ bh,
                                              float* __restrict__ out) {
  __shared__ float Ws[32][128];
  __shared__ float Fs[64][36];
  const int tid = threadIdx.x;
  const int tx = tid & 15, ty = tid >> 4;
  const int rb = blockIdx.x * 64;
  float accz[4][4] = {{0.f}}, acch[4][4] = {{0.f}};

  for (int kc = 0; kc < 160; kc += 32) {
    __syncthreads();
#pragma unroll
    for (int i = 0; i < 4; ++i) {
      int q = tid + i * 256;
      int row = q >> 5, cv = q & 31;
      *(float4*)&Ws[row][cv * 4] = *(const float4*)&Weff[(kc + row) * 128 + cv * 4];
    }
    const int blk = kc >> 5;
    const float* base = (blk == 0) ? X : (blk == 1) ? T1o : (blk == 2) ? T1i : (blk == 3) ? T2o : T2i;
#pragma unroll
    for (int i = 0; i < 2; ++i) {
      int q = tid + i * 256;
      int row = q >> 3, kv = q & 7;
      int gr = rb + row;
      float4 v = make_float4(0.f, 0.f, 0.f, 0.f);
      if (gr < NN) v = *(const float4*)&base[gr * 32 + kv * 4];
      *(float4*)&Fs[row][kv * 4] = v;
    }
    __syncthreads();
#pragma unroll
    for (int k = 0; k < 32; ++k) {
      float fa[4];
#pragma unroll
      for (int ri = 0; ri < 4; ++ri) fa[ri] = Fs[ty * 4 + ri][k];
      float4 wz = *(float4*)&Ws[k][tx * 4];
      float4 wh = *(float4*)&Ws[k][64 + tx * 4];
#pragma unroll
      for (int ri = 0; ri < 4; ++ri) {
        accz[ri][0] += fa[ri] * wz.x; accz[ri][1] += fa[ri] * wz.y;
        accz[ri][2] += fa[ri] * wz.z; accz[ri][3] += fa[ri] * wz.w;
        acch[ri][0] += fa[ri] * wh.x; acch[ri][1] += fa[ri] * wh.y;
        acch[ri][2] += fa[ri] * wh.z; acch[ri][3] += fa[ri] * wh.w;
      }
    }
  }

  const float4 bzv = *(const float4*)&bz[tx * 4];
  const float4 bhv = *(const float4*)&bh[tx * 4];
#pragma unroll
  for (int ri = 0; ri < 4; ++ri) {
    int r = rb + ty * 4 + ri;
    if (r < NN) {
      float4 o;
      float z, h;
      z = 1.f / (1.f + expf(-(accz[ri][0] + bzv.x))); h = tanhf(acch[ri][0] + bhv.x); o.x = (1.f - z) * h;
      z = 1.f / (1.f + expf(-(accz[ri][1] + bzv.y))); h = tanhf(acch[ri][1] + bhv.y); o.y = (1.f - z) * h;
      z = 1.f / (1.f + expf(-(accz[ri][2] + bzv.z))); h = tanhf(acch[ri][2] + bhv.z); o.z = (1.f - z) * h;
      z = 1.f / (1.f + expf(-(accz[ri][3] + bzv.w))); h = tanhf(acch[ri][3] + bhv.w); o.w = (1.f - z) * h;
      *(float4*)&out[r * 64 + tx * 4] = o;
    }
  }
}

// ---------------- launch ----------------
extern "C" void kernel_launch(void* const* d_in, const int* in_sizes, int n_in,
                              void* d_out, int out_size, void* d_ws, size_t ws_size,
                              hipStream_t stream) {
  const float* X  = (const float*)d_in[0];
  const int*   ei = (const int*)d_in[1];
  const float* ew = (const float*)d_in[2];
  const float* Wz = (const float*)d_in[3];
  const float* bz = (const float*)d_in[4];
  const float* Wh = (const float*)d_in[7];
  const float* bh = (const float*)d_in[8];
  float* out = (float*)d_out;
  const int* src = ei;
  const int* dst = ei + NE;

  char* p = (char*)d_ws;
  auto alloc = [&](size_t bytes) -> char* {
    char* r = p;
    p += (bytes + 255) & ~(size_t)255;
    return r;
  };
  float* T1o  = (float*)alloc((size_t)NN * 32 * 4);
  float* T1i  = (float*)alloc((size_t)NN * 32 * 4);
  float* T2o  = (float*)alloc((size_t)NN * 32 * 4);
  float* T2i  = (float*)alloc((size_t)NN * 32 * 4);
  unsigned short* Xh   = (unsigned short*)alloc((size_t)NN * 32 * 2);
  unsigned short* T1oh = (unsigned short*)alloc((size_t)NN * 32 * 2);
  unsigned short* T1ih = (unsigned short*)alloc((size_t)NN * 32 * 2);
  unsigned long long* cmp64 = (unsigned long long*)alloc((size_t)NE * 8);  // coarse-partitioned
  int2*  cmp     = (int2*)alloc((size_t)NE * 8);          // dst-bucketed {e,src}: 6.4 MB
  int2*  cnf     = (int2*)alloc((size_t)NE * 8);
  int2*  cnr     = (int2*)alloc((size_t)NE * 8);
  int*   H       = (int*)alloc((size_t)NBIN * NBLK * 4);  // hist -> scanned positions
  int*   sp      = (int*)alloc((NN + 1) * 4);
  int*   rptr    = (int*)alloc((NN + 1) * 4);
  float* dout    = (float*)alloc(NN * 4);
  float* din     = (float*)alloc(NN * 4);
  float* Weff    = (float*)alloc(160 * 128 * 4);

  // zero device-scope atomics, zero memsets
  k_aux<<<1058, 256, 0, stream>>>(X, src, dst, ew, H, rptr, dout, Wz, Wh, Weff, Xh);
  k_scan<<<1, 1024, 0, stream>>>(H);
  k_part<<<NBLK, 256, 0, stream>>>(src, dst, H, cmp64);
  k_fine<<<NBIN, 1024, 0, stream>>>(H, ew, cmp64, cmp, sp, din);
  k_sortw<<<12500, 256, 0, stream>>>(sp, cmp, src, dout, din, cnf, cnr);  // s0+sort+cnf+cnr

  // T1 = P(Xh) both directions, fp32 out + fp16 copies for the next level
  k_prop2<<<3125, 256, 0, stream>>>(Xh, sp, cnf, T1o, T1oh,
                                    Xh, rptr, cnr, T1i, T1ih, nullptr, 1.f);
  // T2 = 2*P(T1h) - X (fused Chebyshev), fp32 out only
  k_prop2<<<3125, 256, 0, stream>>>(T1oh, sp, cnf, T2o, nullptr,
                                    T1ih, rptr, cnr, T2i, nullptr, X, 2.f);

  k_gemm<<<782, 256, 0, stream>>>(X, T1o, T1i, T2o, T2i, Weff, bz, bh, out);
}

// Round 8
// 249.892 us; speedup vs baseline: 1.4844x; 1.4844x over previous
//
#include <hip/hip_runtime.h>
#include <hip/hip_fp16.h>
#include <cmath>

#define NN 50000
#define NE 800000
#define PADF 96  // fallback local sort cap; P(Poisson(16) > 96) ~ 1e-40
#define NBIN 196     // coarse bins: dst>>8 (dst<50000 -> bin<196)
#define NBLK 391     // edge chunks of 2048 (391*2048 = 800768 >= NE)
#define FCAP 6144    // fine-bucket LDS cap (mean 4082, sigma~64; 6144 = +32 sigma)
// int32-overflow boundary of the reference's argsort key (jax x64 disabled):
// key = dst*50000+src wraps for dst>42949, or dst==42949 && src>=33648.
// VERIFIED (prev session): jax order = rotate(bucket, s0), norm indexed by UNROTATED j
// (rnrm at sorted position idx pairs with j = idx - s0 mod NE, src = RAW src array).
#define DST_HI 42949
#define SRC_CUT 33648
// R4 lesson: every device-scope atomic writes a ~32B HBM sector (1.6M atomics == 51.4MB).
// R5 lesson: a 1-block global scan is 124us of single-CU latency (Amdahl). This version:
// zero device-scope atomics AND fully parallel hierarchical scan (row scans + rowtot).

__device__ __forceinline__ unsigned short f2h(float f) {  // RNE fp32 -> fp16 (11-bit mantissa)
  __half h = __float2half_rn(f);
  return *reinterpret_cast<unsigned short*>(&h);
}

// ---- k_aux: [0,196) rptr+dout | [196,276) Weff | [276,667) X->fp16 | [667,1058) coarse hist.
// Hist: per-chunk LDS histogram of dst>>8, written to H[bin*NBLK+chunk] (coalesced-ish).
__global__ __launch_bounds__(256) void k_aux(const float* __restrict__ X, const int* __restrict__ src,
                                             const int* __restrict__ dst, const float* __restrict__ ew,
                                             int* __restrict__ H,
                                             int* __restrict__ rptr, float* __restrict__ dout,
                                             const float* __restrict__ Wz, const float* __restrict__ Wh,
                                             float* __restrict__ Weff, unsigned short* __restrict__ Xh) {
  __shared__ int hh[256];
  int bid = blockIdx.x;
  int t = threadIdx.x;
  if (bid >= 667) {
    int h = bid - 667;                       // chunk id in [0, NBLK)
    hh[t] = 0;
    __syncthreads();
#pragma unroll
    for (int r = 0; r < 8; ++r) {
      int e = h * 2048 + r * 256 + t;
      if (e < NE) atomicAdd(&hh[dst[e] >> 8], 1);   // LDS atomic only
    }
    __syncthreads();
    if (t < NBIN) H[t * NBLK + h] = hh[t];
  } else if (bid < 196) {
    int i = bid * 256 + t;
    if (i >= NN) return;
    int lo = 0, hi = NE;
    while (lo < hi) { int m = (lo + hi) >> 1; if (src[m] < i) lo = m + 1; else hi = m; }
    int lo2 = lo, hi2 = NE;
    while (lo2 < hi2) { int m = (lo2 + hi2) >> 1; if (src[m] < i + 1) lo2 = m + 1; else hi2 = m; }
    rptr[i] = lo;
    if (i == NN - 1) rptr[NN] = lo2;
    float a = 0.f;
    for (int p = lo; p < lo2; ++p) a += ew[p];
    dout[i] = a;
  } else if (bid < 276) {
    int idx = (bid - 196) * 256 + t;  // 80*256 == 160*128 exactly
    int kk = idx >> 7, f = idx & 127;
    int blk = kk >> 5, c = kk & 31;
    const float* W = (f < 64) ? Wz : Wh;
    int fl = f & 63;
    float v;
    if (blk == 0)      v = W[c * 64 + fl] + W[18432 + c * 64 + fl];
    else if (blk == 1) v = W[6144 + c * 64 + fl];
    else if (blk == 2) v = W[18432 + 6144 + c * 64 + fl];
    else if (blk == 3) v = W[2 * 6144 + c * 64 + fl];
    else               v = W[18432 + 2 * 6144 + c * 64 + fl];
    Weff[idx] = v;
  } else {
    // X -> fp16 copy: 1.6M elems, 16/thread
    int tt = (bid - 276) * 256 + t;
    int base = tt * 16;
    if (base >= NN * 32) return;
#pragma unroll
    for (int q = 0; q < 2; ++q) {
      const float4 a = *(const float4*)&X[base + q * 8];
      const float4 b = *(const float4*)&X[base + q * 8 + 4];
      ushort4 o1 = make_ushort4(f2h(a.x), f2h(a.y), f2h(a.z), f2h(a.w));
      ushort4 o2 = make_ushort4(f2h(b.x), f2h(b.y), f2h(b.z), f2h(b.w));
      *(ushort4*)&Xh[base + q * 8] = o1;
      *(ushort4*)&Xh[base + q * 8 + 4] = o2;
    }
  }
}

// ---- k_scanrow: parallel row-local scan. 196 blocks; block = one bin's 391-chunk row.
// In-place exclusive scan of H[row][0..391) + rowtot[row]. Replaces the 124us 1-block scan. ----
__global__ __launch_bounds__(512) void k_scanrow(int* __restrict__ H, int* __restrict__ rowtot) {
  __shared__ int tmp[512];
  int row = blockIdx.x;
  int t = threadIdx.x;
  int v = (t < NBLK) ? H[row * NBLK + t] : 0;
  tmp[t] = v;
  __syncthreads();
  for (int off = 1; off < 512; off <<= 1) {
    int u = (t >= (unsigned)off) ? tmp[t - off] : 0;
    __syncthreads();
    tmp[t] += u;
    __syncthreads();
  }
  if (t < NBLK) H[row * NBLK + t] = tmp[t] - v;   // exclusive within row
  if (t == 511) rowtot[row] = tmp[511];
}

// ---- k_part: coarse partition by dst>>8. pos = rbase[bin] + Hrow[bin][chunk] + LDS rank
// (unordered rank fine: keys unique). rbase reconstructed per block by a 196-entry LDS scan
// of rowtot (~1us). Packed u64 {dstLow:8 @48, src:16 @24, e:24}. Per-(bin,chunk) runs are
// contiguous (~10 items) -> lines complete in L2 before writeback. ----
__global__ __launch_bounds__(256) void k_part(const int* __restrict__ src, const int* __restrict__ dst,
                                              const int* __restrict__ P, const int* __restrict__ rowtot,
                                              unsigned long long* __restrict__ cmp64) {
  __shared__ int loc[NBIN];
  __shared__ int rs[256];
  __shared__ int rbase[NBIN];
  int h = blockIdx.x;
  int t = threadIdx.x;
  int v = (t < NBIN) ? rowtot[t] : 0;
  rs[t] = v;
  if (t < NBIN) loc[t] = 0;
  __syncthreads();
  for (int off = 1; off < 256; off <<= 1) {
    int u = (t >= (unsigned)off) ? rs[t - off] : 0;
    __syncthreads();
    rs[t] += u;
    __syncthreads();
  }
  if (t < NBIN) rbase[t] = rs[t] - v;   // exclusive scan of rowtot
  __syncthreads();
#pragma unroll
  for (int r = 0; r < 8; ++r) {
    int e = h * 2048 + r * 256 + t;
    if (e < NE) {
      int d = dst[e];
      int bin = d >> 8;
      int rk = atomicAdd(&loc[bin], 1);               // LDS atomic
      int pos = rbase[bin] + P[bin * NBLK + h] + rk;
      cmp64[pos] = ((unsigned long long)(d & 255) << 48) |
                   ((unsigned long long)src[e] << 24) | (unsigned long long)e;
    }
  }
}

// ---- k_fine: one block per coarse bucket (256 dst values). base/end from rowtot (64-lane
// strided sum). In-LDS counting sort by dstLow (unordered ranks), then coalesced emit of
// cmp{e,src}, sp, and din (segmented ew sum). ----
__global__ __launch_bounds__(1024) void k_fine(const int* __restrict__ rowtot, const float* __restrict__ ew,
                                               const unsigned long long* __restrict__ cmp64,
                                               int2* __restrict__ cmp, int* __restrict__ sp,
                                               float* __restrict__ din) {
  __shared__ unsigned long long a1[FCAP], a2[FCAP];
  __shared__ int fh[256], fcnt[256], fo[257];
  __shared__ int bs[2];
  int cb = blockIdx.x;
  int t = threadIdx.x;
  if (t < 64) {
    int s = 0;
    for (int i = t; i < cb; i += 64) s += rowtot[i];
    s += __shfl_xor(s, 32, 64); s += __shfl_xor(s, 16, 64); s += __shfl_xor(s, 8, 64);
    s += __shfl_xor(s, 4, 64);  s += __shfl_xor(s, 2, 64);  s += __shfl_xor(s, 1, 64);
    if (t == 0) { bs[0] = s; bs[1] = s + rowtot[cb]; }
  }
  if (t < 256) { fh[t] = 0; fcnt[t] = 0; }
  __syncthreads();
  int base = bs[0];
  int m = bs[1] - base;
  if (m > FCAP) m = FCAP;                 // paranoia guard
  for (int i = t; i < m; i += 1024) {
    unsigned long long it = cmp64[base + i];
    a1[i] = it;
    atomicAdd(&fh[(int)(it >> 48)], 1);
  }
  __syncthreads();
  // exclusive scan of fh[256] by wave 0 (no barriers needed inside)
  if (t < 64) {
    int v0 = fh[t * 4], v1 = fh[t * 4 + 1], v2 = fh[t * 4 + 2], v3 = fh[t * 4 + 3];
    int s1 = v0 + v1, s2 = s1 + v2, tot = s2 + v3;
    int run = tot;
    for (int off = 1; off < 64; off <<= 1) {
      int v = __shfl_up(run, off, 64);
      if (t >= off) run += v;
    }
    int excl = run - tot;
    fo[t * 4] = excl; fo[t * 4 + 1] = excl + v0; fo[t * 4 + 2] = excl + s1; fo[t * 4 + 3] = excl + s2;
    if (t == 63) fo[256] = excl + tot;    // == m
  }
  __syncthreads();
  // unordered stable-free scatter into a2 (keys unique -> k_sortw's bitonic fixes order)
  for (int i = t; i < m; i += 1024) {
    unsigned long long it = a1[i];
    int b = (int)(it >> 48);
    int p2 = fo[b] + atomicAdd(&fcnt[b], 1);
    a2[p2] = it;
  }
  __syncthreads();
  // emit cmp {e, src} coalesced
  for (int i = t; i < m; i += 1024) {
    unsigned long long it = a2[i];
    cmp[base + i] = make_int2((int)(it & 0xFFFFFF), (int)((it >> 24) & 0xFFFF));
  }
  // emit sp
  if (t < 256) {
    int d = cb * 256 + t;
    if (d <= NN) sp[d] = base + fo[t];
  }
  {
    int d = cb * 256 + t;
    if (t < 257 && d == NN) sp[NN] = base + fo[t];   // cb==195, t==80: fo[80]==m
  }
  // din: 4 lanes per dst, segmented sum of ew over [fo[nd], fo[nd+1])
  int nd = t >> 2, ln = t & 3;
  int d = cb * 256 + nd;
  if (d < NN) {
    float s = 0.f;
    int e0 = fo[nd], e1 = fo[nd + 1];
    for (int i = e0 + ln; i < e1; i += 4) s += ew[(int)(a2[i] & 0xFFFFFF)];
    s += __shfl_down(s, 2, 4);
    s += __shfl_down(s, 1, 4);
    if (ln == 0) din[d] = s;
  }
}

// ---- wave-per-dst: coalesced compact-bucket read -> 64b-key bitonic sort -> cnf
//      (coalesced) + cnr (the ONE scatter). s0 computed inline per block from sp. ----
__global__ __launch_bounds__(256) void k_sortw(const int* __restrict__ sp, const int2* __restrict__ cmp,
                                               const int* __restrict__ rawsrc,
                                               const float* __restrict__ dout, const float* __restrict__ din,
                                               int2* __restrict__ cnf, int2* __restrict__ cnr) {
  __shared__ int s0s;
  {
    int t = threadIdx.x;
    if (t < 64) {
      int b0h = sp[DST_HI];
      int nh = sp[DST_HI + 1] - b0h;
      int c = 0;
      for (int i = t; i < nh; i += 64) c += (cmp[b0h + i].y < SRC_CUT);
      c += __shfl_xor(c, 32, 64); c += __shfl_xor(c, 16, 64); c += __shfl_xor(c, 8, 64);
      c += __shfl_xor(c, 4, 64);  c += __shfl_xor(c, 2, 64);  c += __shfl_xor(c, 1, 64);
      if (t == 0) s0s = b0h + c;
    }
  }
  __syncthreads();
  int wv = (blockIdx.x * 256 + threadIdx.x) >> 6;
  int lane = threadIdx.x & 63;
  if (wv >= NN) return;
  int b0 = sp[wv], b1 = sp[wv + 1];
  int n = b1 - b0;
  int s0 = s0s;
  if (n > 64) {  // 64<n<=96 safety path (never hit at Poisson(16))
    if (lane == 0) {
      int es[PADF], ss[PADF];
      int nn = n > PADF ? PADF : n;
      for (int i = 0; i < nn; ++i) { int2 pe = cmp[b0 + i]; es[i] = pe.x; ss[i] = pe.y; }
      for (int i = 1; i < nn; ++i) {
        int ve = es[i], vs = ss[i]; int j = i - 1;
        while (j >= 0 && es[j] > ve) { es[j + 1] = es[j]; ss[j + 1] = ss[j]; --j; }
        es[j + 1] = ve; ss[j + 1] = vs;
      }
      for (int i = 0; i < nn; ++i) {
        int vs = ss[i];
        cnf[b0 + i] = make_int2(vs, __float_as_int(1.0f / dout[vs]));
        int j = b0 + i - s0; if (j < 0) j += NE;
        cnr[es[i]] = make_int2(wv, __float_as_int(1.0f / din[rawsrc[j]]));
      }
    }
    return;
  }
  unsigned long long k = ~0ULL;
  if (lane < n) {
    int2 pe = cmp[b0 + lane];   // coalesced contiguous read
    k = ((unsigned long long)(unsigned)pe.x << 32) | (unsigned)pe.y;  // key=e, payload=src
  }
  if (n > 1) {
#pragma unroll
    for (int kk = 2; kk <= 64; kk <<= 1) {
#pragma unroll
      for (int j = kk >> 1; j > 0; j >>= 1) {
        unsigned long long o = __shfl_xor(k, j, 64);
        bool lower = (lane & j) == 0;
        bool asc = (lane & kk) == 0;
        bool keepmin = (lower == asc);
        if (keepmin ? (o < k) : (o > k)) k = o;
      }
    }
  }
  if (lane < n) {
    int ve = (int)(k >> 32);
    int vs = (int)(k & 0xffffffffu);
    cnf[b0 + lane] = make_int2(vs, __float_as_int(1.0f / dout[vs]));   // coalesced
    int j = b0 + lane - s0; if (j < 0) j += NE;
    cnr[ve] = make_int2(wv, __float_as_int(1.0f / din[rawsrc[j]]));    // the one scatter
  }
}

// ---- fused pair of gather props, FP16 gather operand (1 line/row vs 2; Xh fits XCD L2;
//      11-bit mantissa: ~8x less rounding than the failed bf16 — lesson R13):
//      accumulate fp32, out fp32 (+ optional fp16 copy for the next prop level). ----
__global__ __launch_bounds__(256) void k_prop2(const unsigned short* __restrict__ inA, const int* __restrict__ rpA,
                                               const int2* __restrict__ cnA, float* __restrict__ outA,
                                               unsigned short* __restrict__ outAh,
                                               const unsigned short* __restrict__ inB, const int* __restrict__ rpB,
                                               const int2* __restrict__ cnB, float* __restrict__ outB,
                                               unsigned short* __restrict__ outBh,
                                               const float* __restrict__ sub, float mul) {
  int t = blockIdx.x * 256 + threadIdx.x;
  const int half = NN * 8;
  const unsigned short* in; const int* rp; const int2* cn; float* out; unsigned short* outh;
  if (t < half) { in = inA; rp = rpA; cn = cnA; out = outA; outh = outAh; }
  else          { in = inB; rp = rpB; cn = cnB; out = outB; outh = outBh; t -= half; }
  int r = t >> 3;
  if (r >= NN) return;
  int lane8 = t & 7;
  int c4 = lane8 * 4;
  int b = rp[r], e2 = rp[r + 1];
  float a0[4] = {0.f, 0.f, 0.f, 0.f}, a1[4] = {0.f, 0.f, 0.f, 0.f};
  int p = b;
#define GATH(cc, ww) { \
    uint2 bv = *(const uint2*)&in[(cc) * 32 + c4]; \
    float2 f01 = __half22float2(*(const __half2*)&bv.x); \
    float2 f23 = __half22float2(*(const __half2*)&bv.y); \
    float* a = (jj & 1) ? a1 : a0; \
    a[0] += (ww) * f01.x; a[1] += (ww) * f01.y; \
    a[2] += (ww) * f23.x; a[3] += (ww) * f23.y; }
  for (; p + 16 <= e2; p += 16) {
    int2 u = cn[p + lane8];              // both chunk-loads in flight before any gather
    int2 v = cn[p + 8 + lane8];
#pragma unroll
    for (int jj = 0; jj < 8; ++jj) {
      int col = __shfl(u.x, jj, 8);
      float w = __int_as_float(__shfl(u.y, jj, 8));
      GATH(col, w)
    }
#pragma unroll
    for (int jj = 0; jj < 8; ++jj) {
      int col = __shfl(v.x, jj, 8);
      float w = __int_as_float(__shfl(v.y, jj, 8));
      GATH(col, w)
    }
  }
  for (; p + 8 <= e2; p += 8) {
    int2 u = cn[p + lane8];
#pragma unroll
    for (int jj = 0; jj < 8; ++jj) {
      int col = __shfl(u.x, jj, 8);
      float w = __int_as_float(__shfl(u.y, jj, 8));
      GATH(col, w)
    }
  }
  for (int jj = 0; p < e2; ++p) {
    int2 c1 = cn[p];
    float w = __int_as_float(c1.y);
    GATH(c1.x, w)
  }
#undef GATH
  float ax = a0[0] + a1[0], ay = a0[1] + a1[1], az = a0[2] + a1[2], aw = a0[3] + a1[3];
  float4 o;
  if (sub) {
    const float4 s = *(const float4*)&sub[r * 32 + c4];
    o.x = mul * ax - s.x; o.y = mul * ay - s.y; o.z = mul * az - s.z; o.w = mul * aw - s.w;
  } else {
    o.x = ax; o.y = ay; o.z = az; o.w = aw;
  }
  *(float4*)&out[r * 32 + c4] = o;
  if (outh) {
    ushort4 oh = make_ushort4(f2h(o.x), f2h(o.y), f2h(o.z), f2h(o.w));
    *(ushort4*)&outh[r * 32 + c4] = oh;
  }
}

// ---- register-blocked GEMM + GRU epilogue: 64x128 tile, K-chunk 32 (25.6 KB LDS) ----
__global__ __launch_bounds__(256) void k_gemm(const float* __restrict__ X, const float* __restrict__ T1o,
                                              const float* __restrict__ T1i, const float* __restrict__ T2o,
                                              const float* __restrict__ T2i,
                                              const float* __restrict__ Weff,
                                              const float* __restrict__ bz, const float* __restrict__ bh,
                                              float* __restrict__ out) {
  __shared__ float Ws[32][128];
  __shared__ float Fs[64][36];
  const int tid = threadIdx.x;
  const int tx = tid & 15, ty = tid >> 4;
  const int rb = blockIdx.x * 64;
  float accz[4][4] = {{0.f}}, acch[4][4] = {{0.f}};

  for (int kc = 0; kc < 160; kc += 32) {
    __syncthreads();
#pragma unroll
    for (int i = 0; i < 4; ++i) {
      int q = tid + i * 256;
      int row = q >> 5, cv = q & 31;
      *(float4*)&Ws[row][cv * 4] = *(const float4*)&Weff[(kc + row) * 128 + cv * 4];
    }
    const int blk = kc >> 5;
    const float* base = (blk == 0) ? X : (blk == 1) ? T1o : (blk == 2) ? T1i : (blk == 3) ? T2o : T2i;
#pragma unroll
    for (int i = 0; i < 2; ++i) {
      int q = tid + i * 256;
      int row = q >> 3, kv = q & 7;
      int gr = rb + row;
      float4 v = make_float4(0.f, 0.f, 0.f, 0.f);
      if (gr < NN) v = *(const float4*)&base[gr * 32 + kv * 4];
      *(float4*)&Fs[row][kv * 4] = v;
    }
    __syncthreads();
#pragma unroll
    for (int k = 0; k < 32; ++k) {
      float fa[4];
#pragma unroll
      for (int ri = 0; ri < 4; ++ri) fa[ri] = Fs[ty * 4 + ri][k];
      float4 wz = *(float4*)&Ws[k][tx * 4];
      float4 wh = *(float4*)&Ws[k][64 + tx * 4];
#pragma unroll
      for (int ri = 0; ri < 4; ++ri) {
        accz[ri][0] += fa[ri] * wz.x; accz[ri][1] += fa[ri] * wz.y;
        accz[ri][2] += fa[ri] * wz.z; accz[ri][3] += fa[ri] * wz.w;
        acch[ri][0] += fa[ri] * wh.x; acch[ri][1] += fa[ri] * wh.y;
        acch[ri][2] += fa[ri] * wh.z; acch[ri][3] += fa[ri] * wh.w;
      }
    }
  }

  const float4 bzv = *(const float4*)&bz[tx * 4];
  const float4 bhv = *(const float4*)&bh[tx * 4];
#pragma unroll
  for (int ri = 0; ri < 4; ++ri) {
    int r = rb + ty * 4 + ri;
    if (r < NN) {
      float4 o;
      float z, h;
      z = 1.f / (1.f + expf(-(accz[ri][0] + bzv.x))); h = tanhf(acch[ri][0] + bhv.x); o.x = (1.f - z) * h;
      z = 1.f / (1.f + expf(-(accz[ri][1] + bzv.y))); h = tanhf(acch[ri][1] + bhv.y); o.y = (1.f - z) * h;
      z = 1.f / (1.f + expf(-(accz[ri][2] + bzv.z))); h = tanhf(acch[ri][2] + bhv.z); o.z = (1.f - z) * h;
      z = 1.f / (1.f + expf(-(accz[ri][3] + bzv.w))); h = tanhf(acch[ri][3] + bhv.w); o.w = (1.f - z) * h;
      *(float4*)&out[r * 64 + tx * 4] = o;
    }
  }
}

// ---------------- launch ----------------
extern "C" void kernel_launch(void* const* d_in, const int* in_sizes, int n_in,
                              void* d_out, int out_size, void* d_ws, size_t ws_size,
                              hipStream_t stream) {
  const float* X  = (const float*)d_in[0];
  const int*   ei = (const int*)d_in[1];
  const float* ew = (const float*)d_in[2];
  const float* Wz = (const float*)d_in[3];
  const float* bz = (const float*)d_in[4];
  const float* Wh = (const float*)d_in[7];
  const float* bh = (const float*)d_in[8];
  float* out = (float*)d_out;
  const int* src = ei;
  const int* dst = ei + NE;

  char* p = (char*)d_ws;
  auto alloc = [&](size_t bytes) -> char* {
    char* r = p;
    p += (bytes + 255) & ~(size_t)255;
    return r;
  };
  float* T1o  = (float*)alloc((size_t)NN * 32 * 4);
  float* T1i  = (float*)alloc((size_t)NN * 32 * 4);
  float* T2o  = (float*)alloc((size_t)NN * 32 * 4);
  float* T2i  = (float*)alloc((size_t)NN * 32 * 4);
  unsigned short* Xh   = (unsigned short*)alloc((size_t)NN * 32 * 2);
  unsigned short* T1oh = (unsigned short*)alloc((size_t)NN * 32 * 2);
  unsigned short* T1ih = (unsigned short*)alloc((size_t)NN * 32 * 2);
  unsigned long long* cmp64 = (unsigned long long*)alloc((size_t)NE * 8);  // coarse-partitioned
  int2*  cmp     = (int2*)alloc((size_t)NE * 8);          // dst-bucketed {e,src}: 6.4 MB
  int2*  cnf     = (int2*)alloc((size_t)NE * 8);
  int2*  cnr     = (int2*)alloc((size_t)NE * 8);
  int*   H       = (int*)alloc((size_t)NBIN * NBLK * 4);  // hist -> row-exclusive prefixes
  int*   rowtot  = (int*)alloc(NBIN * 4);
  int*   sp      = (int*)alloc((NN + 1) * 4);
  int*   rptr    = (int*)alloc((NN + 1) * 4);
  float* dout    = (float*)alloc(NN * 4);
  float* din     = (float*)alloc(NN * 4);
  float* Weff    = (float*)alloc(160 * 128 * 4);

  // zero device-scope atomics, zero memsets, fully parallel scan
  k_aux<<<1058, 256, 0, stream>>>(X, src, dst, ew, H, rptr, dout, Wz, Wh, Weff, Xh);
  k_scanrow<<<NBIN, 512, 0, stream>>>(H, rowtot);
  k_part<<<NBLK, 256, 0, stream>>>(src, dst, H, rowtot, cmp64);
  k_fine<<<NBIN, 1024, 0, stream>>>(rowtot, ew, cmp64, cmp, sp, din);
  k_sortw<<<12500, 256, 0, stream>>>(sp, cmp, src, dout, din, cnf, cnr);  // s0+sort+cnf+cnr

  // T1 = P(Xh) both directions, fp32 out + fp16 copies for the next level
  k_prop2<<<3125, 256, 0, stream>>>(Xh, sp, cnf, T1o, T1oh,
                                    Xh, rptr, cnr, T1i, T1ih, nullptr, 1.f);
  // T2 = 2*P(T1h) - X (fused Chebyshev), fp32 out only
  k_prop2<<<3125, 256, 0, stream>>>(T1oh, sp, cnf, T2o, nullptr,
                                    T1ih, rptr, cnr, T2i, nullptr, X, 2.f);

  k_gemm<<<782, 256, 0, stream>>>(X, T1o, T1i, T2o, T2i, Weff, bz, bh, out);
}

// Round 9
// 233.368 us; speedup vs baseline: 1.5895x; 1.0708x over previous
//
#include <hip/hip_runtime.h>
#include <hip/hip_fp16.h>
#include <cmath>

#define NN 50000
#define NE 800000
#define PADF 96  // fallback local sort cap; P(Poisson(16) > 96) ~ 1e-40
#define NBIN 196     // coarse bins: dst>>8 (dst<50000 -> bin<196)
#define NBLK 391     // edge chunks of 2048 (391*2048 = 800768 >= NE)
#define FCAP 6144    // fine-bucket LDS cap (mean 4082, sigma~64; 6144 = +32 sigma)
// int32-overflow boundary of the reference's argsort key (jax x64 disabled):
// key = dst*50000+src wraps for dst>42949, or dst==42949 && src>=33648.
// VERIFIED (prev session): jax order = rotate(bucket, s0), norm indexed by UNROTATED j
// (rnrm at sorted position idx pairs with j = idx - s0 mod NE, src = RAW src array).
#define DST_HI 42949
#define SRC_CUT 33648
// R4 lesson: device-scope atomics write ~32B HBM sectors (1.6M atomics == 51.4MB).
// R5 lesson: 1-block global scan = 124us single-CU Amdahl -> hierarchical scan (R8: works).
// R8 lesson: steady-state top kernel = fp32 vector k_gemm (46us, MfmaUtil 0). This round:
// fp16 MFMA gemm (16x16x16_f16), fp16-only prop outputs, Weff transposed fp16.

__device__ __forceinline__ unsigned short f2h(float f) {  // RNE fp32 -> fp16 (11-bit mantissa)
  __half h = __float2half_rn(f);
  return *reinterpret_cast<unsigned short*>(&h);
}

typedef _Float16 half4 __attribute__((ext_vector_type(4)));
typedef float f32x4 __attribute__((ext_vector_type(4)));

// ---- k_aux: [0,196) rptr+dout | [196,276) WT fp16 transposed | [276,667) X->fp16 | [667,1058) hist.
__global__ __launch_bounds__(256) void k_aux(const float* __restrict__ X, const int* __restrict__ src,
                                             const int* __restrict__ dst, const float* __restrict__ ew,
                                             int* __restrict__ H,
                                             int* __restrict__ rptr, float* __restrict__ dout,
                                             const float* __restrict__ Wz, const float* __restrict__ Wh,
                                             unsigned short* __restrict__ WT, unsigned short* __restrict__ Xh) {
  __shared__ int hh[256];
  int bid = blockIdx.x;
  int t = threadIdx.x;
  if (bid >= 667) {
    int h = bid - 667;                       // chunk id in [0, NBLK)
    hh[t] = 0;
    __syncthreads();
#pragma unroll
    for (int r = 0; r < 8; ++r) {
      int e = h * 2048 + r * 256 + t;
      if (e < NE) atomicAdd(&hh[dst[e] >> 8], 1);   // LDS atomic only
    }
    __syncthreads();
    if (t < NBIN) H[t * NBLK + h] = hh[t];
  } else if (bid < 196) {
    int i = bid * 256 + t;
    if (i >= NN) return;
    int lo = 0, hi = NE;
    while (lo < hi) { int m = (lo + hi) >> 1; if (src[m] < i) lo = m + 1; else hi = m; }
    int lo2 = lo, hi2 = NE;
    while (lo2 < hi2) { int m = (lo2 + hi2) >> 1; if (src[m] < i + 1) lo2 = m + 1; else hi2 = m; }
    rptr[i] = lo;
    if (i == NN - 1) rptr[NN] = lo2;
    float a = 0.f;
    for (int p = lo; p < lo2; ++p) a += ew[p];
    dout[i] = a;
  } else if (bid < 276) {
    int idx = (bid - 196) * 256 + t;  // 80*256 == 160*128 exactly
    int kk = idx >> 7, f = idx & 127;
    int blk = kk >> 5, c = kk & 31;
    const float* W = (f < 64) ? Wz : Wh;
    int fl = f & 63;
    float v;
    if (blk == 0)      v = W[c * 64 + fl] + W[18432 + c * 64 + fl];
    else if (blk == 1) v = W[6144 + c * 64 + fl];
    else if (blk == 2) v = W[18432 + 6144 + c * 64 + fl];
    else if (blk == 3) v = W[2 * 6144 + c * 64 + fl];
    else               v = W[18432 + 2 * 6144 + c * 64 + fl];
    WT[f * 160 + kk] = f2h(v);     // transposed fp16: [n=128][k=160], MFMA B-frag k-contig
  } else {
    // X -> fp16 copy: 1.6M elems, 16/thread
    int tt = (bid - 276) * 256 + t;
    int base = tt * 16;
    if (base >= NN * 32) return;
#pragma unroll
    for (int q = 0; q < 2; ++q) {
      const float4 a = *(const float4*)&X[base + q * 8];
      const float4 b = *(const float4*)&X[base + q * 8 + 4];
      ushort4 o1 = make_ushort4(f2h(a.x), f2h(a.y), f2h(a.z), f2h(a.w));
      ushort4 o2 = make_ushort4(f2h(b.x), f2h(b.y), f2h(b.z), f2h(b.w));
      *(ushort4*)&Xh[base + q * 8] = o1;
      *(ushort4*)&Xh[base + q * 8 + 4] = o2;
    }
  }
}

// ---- k_scanrow: parallel row-local scan. 196 blocks; block = one bin's 391-chunk row. ----
__global__ __launch_bounds__(512) void k_scanrow(int* __restrict__ H, int* __restrict__ rowtot) {
  __shared__ int tmp[512];
  int row = blockIdx.x;
  int t = threadIdx.x;
  int v = (t < NBLK) ? H[row * NBLK + t] : 0;
  tmp[t] = v;
  __syncthreads();
  for (int off = 1; off < 512; off <<= 1) {
    int u = (t >= (unsigned)off) ? tmp[t - off] : 0;
    __syncthreads();
    tmp[t] += u;
    __syncthreads();
  }
  if (t < NBLK) H[row * NBLK + t] = tmp[t] - v;   // exclusive within row
  if (t == 511) rowtot[row] = tmp[511];
}

// ---- k_part: coarse partition by dst>>8. pos = rbase[bin] + Hrow[bin][chunk] + LDS rank. ----
__global__ __launch_bounds__(256) void k_part(const int* __restrict__ src, const int* __restrict__ dst,
                                              const int* __restrict__ P, const int* __restrict__ rowtot,
                                              unsigned long long* __restrict__ cmp64) {
  __shared__ int loc[NBIN];
  __shared__ int rs[256];
  __shared__ int rbase[NBIN];
  int h = blockIdx.x;
  int t = threadIdx.x;
  int v = (t < NBIN) ? rowtot[t] : 0;
  rs[t] = v;
  if (t < NBIN) loc[t] = 0;
  __syncthreads();
  for (int off = 1; off < 256; off <<= 1) {
    int u = (t >= (unsigned)off) ? rs[t - off] : 0;
    __syncthreads();
    rs[t] += u;
    __syncthreads();
  }
  if (t < NBIN) rbase[t] = rs[t] - v;   // exclusive scan of rowtot
  __syncthreads();
#pragma unroll
  for (int r = 0; r < 8; ++r) {
    int e = h * 2048 + r * 256 + t;
    if (e < NE) {
      int d = dst[e];
      int bin = d >> 8;
      int rk = atomicAdd(&loc[bin], 1);               // LDS atomic
      int pos = rbase[bin] + P[bin * NBLK + h] + rk;
      cmp64[pos] = ((unsigned long long)(d & 255) << 48) |
                   ((unsigned long long)src[e] << 24) | (unsigned long long)e;
    }
  }
}

// ---- k_fine: one block per coarse bucket. In-LDS counting sort by dstLow, emit cmp/sp/din. ----
__global__ __launch_bounds__(1024) void k_fine(const int* __restrict__ rowtot, const float* __restrict__ ew,
                                               const unsigned long long* __restrict__ cmp64,
                                               int2* __restrict__ cmp, int* __restrict__ sp,
                                               float* __restrict__ din) {
  __shared__ unsigned long long a1[FCAP], a2[FCAP];
  __shared__ int fh[256], fcnt[256], fo[257];
  __shared__ int bs[2];
  int cb = blockIdx.x;
  int t = threadIdx.x;
  if (t < 64) {
    int s = 0;
    for (int i = t; i < cb; i += 64) s += rowtot[i];
    s += __shfl_xor(s, 32, 64); s += __shfl_xor(s, 16, 64); s += __shfl_xor(s, 8, 64);
    s += __shfl_xor(s, 4, 64);  s += __shfl_xor(s, 2, 64);  s += __shfl_xor(s, 1, 64);
    if (t == 0) { bs[0] = s; bs[1] = s + rowtot[cb]; }
  }
  if (t < 256) { fh[t] = 0; fcnt[t] = 0; }
  __syncthreads();
  int base = bs[0];
  int m = bs[1] - base;
  if (m > FCAP) m = FCAP;                 // paranoia guard
  for (int i = t; i < m; i += 1024) {
    unsigned long long it = cmp64[base + i];
    a1[i] = it;
    atomicAdd(&fh[(int)(it >> 48)], 1);
  }
  __syncthreads();
  if (t < 64) {
    int v0 = fh[t * 4], v1 = fh[t * 4 + 1], v2 = fh[t * 4 + 2], v3 = fh[t * 4 + 3];
    int s1 = v0 + v1, s2 = s1 + v2, tot = s2 + v3;
    int run = tot;
    for (int off = 1; off < 64; off <<= 1) {
      int v = __shfl_up(run, off, 64);
      if (t >= off) run += v;
    }
    int excl = run - tot;
    fo[t * 4] = excl; fo[t * 4 + 1] = excl + v0; fo[t * 4 + 2] = excl + s1; fo[t * 4 + 3] = excl + s2;
    if (t == 63) fo[256] = excl + tot;    // == m
  }
  __syncthreads();
  for (int i = t; i < m; i += 1024) {
    unsigned long long it = a1[i];
    int b = (int)(it >> 48);
    int p2 = fo[b] + atomicAdd(&fcnt[b], 1);
    a2[p2] = it;
  }
  __syncthreads();
  for (int i = t; i < m; i += 1024) {
    unsigned long long it = a2[i];
    cmp[base + i] = make_int2((int)(it & 0xFFFFFF), (int)((it >> 24) & 0xFFFF));
  }
  if (t < 256) {
    int d = cb * 256 + t;
    if (d <= NN) sp[d] = base + fo[t];
  }
  {
    int d = cb * 256 + t;
    if (t < 257 && d == NN) sp[NN] = base + fo[t];   // cb==195, t==80: fo[80]==m
  }
  int nd = t >> 2, ln = t & 3;
  int d = cb * 256 + nd;
  if (d < NN) {
    float s = 0.f;
    int e0 = fo[nd], e1 = fo[nd + 1];
    for (int i = e0 + ln; i < e1; i += 4) s += ew[(int)(a2[i] & 0xFFFFFF)];
    s += __shfl_down(s, 2, 4);
    s += __shfl_down(s, 1, 4);
    if (ln == 0) din[d] = s;
  }
}

// ---- wave-per-dst: bitonic sort -> cnf (coalesced) + cnr (the one scatter). ----
__global__ __launch_bounds__(256) void k_sortw(const int* __restrict__ sp, const int2* __restrict__ cmp,
                                               const int* __restrict__ rawsrc,
                                               const float* __restrict__ dout, const float* __restrict__ din,
                                               int2* __restrict__ cnf, int2* __restrict__ cnr) {
  __shared__ int s0s;
  {
    int t = threadIdx.x;
    if (t < 64) {
      int b0h = sp[DST_HI];
      int nh = sp[DST_HI + 1] - b0h;
      int c = 0;
      for (int i = t; i < nh; i += 64) c += (cmp[b0h + i].y < SRC_CUT);
      c += __shfl_xor(c, 32, 64); c += __shfl_xor(c, 16, 64); c += __shfl_xor(c, 8, 64);
      c += __shfl_xor(c, 4, 64);  c += __shfl_xor(c, 2, 64);  c += __shfl_xor(c, 1, 64);
      if (t == 0) s0s = b0h + c;
    }
  }
  __syncthreads();
  int wv = (blockIdx.x * 256 + threadIdx.x) >> 6;
  int lane = threadIdx.x & 63;
  if (wv >= NN) return;
  int b0 = sp[wv], b1 = sp[wv + 1];
  int n = b1 - b0;
  int s0 = s0s;
  if (n > 64) {  // 64<n<=96 safety path (never hit at Poisson(16))
    if (lane == 0) {
      int es[PADF], ss[PADF];
      int nn = n > PADF ? PADF : n;
      for (int i = 0; i < nn; ++i) { int2 pe = cmp[b0 + i]; es[i] = pe.x; ss[i] = pe.y; }
      for (int i = 1; i < nn; ++i) {
        int ve = es[i], vs = ss[i]; int j = i - 1;
        while (j >= 0 && es[j] > ve) { es[j + 1] = es[j]; ss[j + 1] = ss[j]; --j; }
        es[j + 1] = ve; ss[j + 1] = vs;
      }
      for (int i = 0; i < nn; ++i) {
        int vs = ss[i];
        cnf[b0 + i] = make_int2(vs, __float_as_int(1.0f / dout[vs]));
        int j = b0 + i - s0; if (j < 0) j += NE;
        cnr[es[i]] = make_int2(wv, __float_as_int(1.0f / din[rawsrc[j]]));
      }
    }
    return;
  }
  unsigned long long k = ~0ULL;
  if (lane < n) {
    int2 pe = cmp[b0 + lane];   // coalesced contiguous read
    k = ((unsigned long long)(unsigned)pe.x << 32) | (unsigned)pe.y;  // key=e, payload=src
  }
  if (n > 1) {
#pragma unroll
    for (int kk = 2; kk <= 64; kk <<= 1) {
#pragma unroll
      for (int j = kk >> 1; j > 0; j >>= 1) {
        unsigned long long o = __shfl_xor(k, j, 64);
        bool lower = (lane & j) == 0;
        bool asc = (lane & kk) == 0;
        bool keepmin = (lower == asc);
        if (keepmin ? (o < k) : (o > k)) k = o;
      }
    }
  }
  if (lane < n) {
    int ve = (int)(k >> 32);
    int vs = (int)(k & 0xffffffffu);
    cnf[b0 + lane] = make_int2(vs, __float_as_int(1.0f / dout[vs]));   // coalesced
    int j = b0 + lane - s0; if (j < 0) j += NE;
    cnr[ve] = make_int2(wv, __float_as_int(1.0f / din[rawsrc[j]]));    // the one scatter
  }
}

// ---- fused pair of gather props, FP16 gather operand; fp16-only outputs now (fp32 outs
//      had no consumer once the GEMM reads fp16 — saves ~19 MB of writes). ----
__global__ __launch_bounds__(256) void k_prop2(const unsigned short* __restrict__ inA, const int* __restrict__ rpA,
                                               const int2* __restrict__ cnA, float* __restrict__ outA,
                                               unsigned short* __restrict__ outAh,
                                               const unsigned short* __restrict__ inB, const int* __restrict__ rpB,
                                               const int2* __restrict__ cnB, float* __restrict__ outB,
                                               unsigned short* __restrict__ outBh,
                                               const float* __restrict__ sub, float mul) {
  int t = blockIdx.x * 256 + threadIdx.x;
  const int half = NN * 8;
  const unsigned short* in; const int* rp; const int2* cn; float* out; unsigned short* outh;
  if (t < half) { in = inA; rp = rpA; cn = cnA; out = outA; outh = outAh; }
  else          { in = inB; rp = rpB; cn = cnB; out = outB; outh = outBh; t -= half; }
  int r = t >> 3;
  if (r >= NN) return;
  int lane8 = t & 7;
  int c4 = lane8 * 4;
  int b = rp[r], e2 = rp[r + 1];
  float a0[4] = {0.f, 0.f, 0.f, 0.f}, a1[4] = {0.f, 0.f, 0.f, 0.f};
  int p = b;
#define GATH(cc, ww) { \
    uint2 bv = *(const uint2*)&in[(cc) * 32 + c4]; \
    float2 f01 = __half22float2(*(const __half2*)&bv.x); \
    float2 f23 = __half22float2(*(const __half2*)&bv.y); \
    float* a = (jj & 1) ? a1 : a0; \
    a[0] += (ww) * f01.x; a[1] += (ww) * f01.y; \
    a[2] += (ww) * f23.x; a[3] += (ww) * f23.y; }
  for (; p + 16 <= e2; p += 16) {
    int2 u = cn[p + lane8];              // both chunk-loads in flight before any gather
    int2 v = cn[p + 8 + lane8];
#pragma unroll
    for (int jj = 0; jj < 8; ++jj) {
      int col = __shfl(u.x, jj, 8);
      float w = __int_as_float(__shfl(u.y, jj, 8));
      GATH(col, w)
    }
#pragma unroll
    for (int jj = 0; jj < 8; ++jj) {
      int col = __shfl(v.x, jj, 8);
      float w = __int_as_float(__shfl(v.y, jj, 8));
      GATH(col, w)
    }
  }
  for (; p + 8 <= e2; p += 8) {
    int2 u = cn[p + lane8];
#pragma unroll
    for (int jj = 0; jj < 8; ++jj) {
      int col = __shfl(u.x, jj, 8);
      float w = __int_as_float(__shfl(u.y, jj, 8));
      GATH(col, w)
    }
  }
  for (int jj = 0; p < e2; ++p) {
    int2 c1 = cn[p];
    float w = __int_as_float(c1.y);
    GATH(c1.x, w)
  }
#undef GATH
  float ax = a0[0] + a1[0], ay = a0[1] + a1[1], az = a0[2] + a1[2], aw = a0[3] + a1[3];
  float4 o;
  if (sub) {
    const float4 s = *(const float4*)&sub[r * 32 + c4];
    o.x = mul * ax - s.x; o.y = mul * ay - s.y; o.z = mul * az - s.z; o.w = mul * aw - s.w;
  } else {
    o.x = ax; o.y = ay; o.z = az; o.w = aw;
  }
  if (out) *(float4*)&out[r * 32 + c4] = o;
  if (outh) {
    ushort4 oh = make_ushort4(f2h(o.x), f2h(o.y), f2h(o.z), f2h(o.w));
    *(ushort4*)&outh[r * 32 + c4] = oh;
  }
}

// ---- MFMA fp16 GEMM + GRU epilogue. Block = 4 waves, 64 rows; wave = 16 rows x 128 cols.
// v_mfma_f32_16x16x16_f16 classic layout: A[row=l&15][k=(l>>4)*4+i], B[k=(l>>4)*4+i][col=l&15],
// D[row=(l>>4)*4+i][col=l&15] (guide-verified C/D for 16x16). A-frags straight from global
// (L1/L2-served, 2 k-steps reuse each 64B row-line); B staged in LDS [128][168] (pad 168:
// row-stride 336B -> bank step 20 -> 2-way, free). z-tile t pairs with h-tile t+4 at same
// (row,col) per lane -> GRU epilogue is lane-local. ----
__global__ __launch_bounds__(256) void k_gemm(const unsigned short* __restrict__ Xh,
                                              const unsigned short* __restrict__ T1oh,
                                              const unsigned short* __restrict__ T1ih,
                                              const unsigned short* __restrict__ T2oh,
                                              const unsigned short* __restrict__ T2ih,
                                              const unsigned short* __restrict__ WT,
                                              const float* __restrict__ bz, const float* __restrict__ bh,
                                              float* __restrict__ out) {
  __shared__ unsigned short wlds[128 * 168];
  const int tid = threadIdx.x;
  for (int i = tid; i < 128 * 20; i += 256) {     // 160 halves = 20 x uint4 per row
    int n = i / 20, o = i % 20;
    *(uint4*)&wlds[n * 168 + o * 8] = *(const uint4*)&WT[n * 160 + o * 8];
  }
  __syncthreads();
  const int l = tid & 63, wid = tid >> 6;
  const int m0 = wid * 16;
  const int rb = blockIdx.x * 64;
  int grow = rb + m0 + (l & 15); if (grow >= NN) grow = NN - 1;   // clamp loads; stores guarded
  const int kg = (l >> 4) * 4;
  f32x4 acc[8];
#pragma unroll
  for (int t = 0; t < 8; ++t) acc[t] = (f32x4){0.f, 0.f, 0.f, 0.f};
  const unsigned short* srcs[5] = {Xh, T1oh, T1ih, T2oh, T2ih};
#pragma unroll
  for (int s = 0; s < 5; ++s) {
    const unsigned short* A = srcs[s];
#pragma unroll
    for (int h2 = 0; h2 < 2; ++h2) {
      const int kk = h2 * 16;
      half4 af = *(const half4*)&A[grow * 32 + kk + kg];
      const int kglob = s * 32 + kk + kg;
#pragma unroll
      for (int t = 0; t < 8; ++t) {
        half4 bf = *(const half4*)&wlds[(t * 16 + (l & 15)) * 168 + kglob];
        acc[t] = __builtin_amdgcn_mfma_f32_16x16x16f16(af, bf, acc[t], 0, 0, 0);
      }
    }
  }
  const int c = l & 15;
#pragma unroll
  for (int t = 0; t < 4; ++t) {
    int col = t * 16 + c;
    float bzv = bz[col], bhv = bh[col];
#pragma unroll
    for (int i = 0; i < 4; ++i) {
      int r = rb + m0 + (l >> 4) * 4 + i;
      if (r < NN) {
        float z = 1.f / (1.f + expf(-(acc[t][i] + bzv)));
        float hv = tanhf(acc[t + 4][i] + bhv);
        out[r * 64 + col] = (1.f - z) * hv;
      }
    }
  }
}

// ---------------- launch ----------------
extern "C" void kernel_launch(void* const* d_in, const int* in_sizes, int n_in,
                              void* d_out, int out_size, void* d_ws, size_t ws_size,
                              hipStream_t stream) {
  const float* X  = (const float*)d_in[0];
  const int*   ei = (const int*)d_in[1];
  const float* ew = (const float*)d_in[2];
  const float* Wz = (const float*)d_in[3];
  const float* bz = (const float*)d_in[4];
  const float* Wh = (const float*)d_in[7];
  const float* bh = (const float*)d_in[8];
  float* out = (float*)d_out;
  const int* src = ei;
  const int* dst = ei + NE;

  char* p = (char*)d_ws;
  auto alloc = [&](size_t bytes) -> char* {
    char* r = p;
    p += (bytes + 255) & ~(size_t)255;
    return r;
  };
  unsigned short* Xh   = (unsigned short*)alloc((size_t)NN * 32 * 2);
  unsigned short* T1oh = (unsigned short*)alloc((size_t)NN * 32 * 2);
  unsigned short* T1ih = (unsigned short*)alloc((size_t)NN * 32 * 2);
  unsigned short* T2oh = (unsigned short*)alloc((size_t)NN * 32 * 2);
  unsigned short* T2ih = (unsigned short*)alloc((size_t)NN * 32 * 2);
  unsigned long long* cmp64 = (unsigned long long*)alloc((size_t)NE * 8);  // coarse-partitioned
  int2*  cmp     = (int2*)alloc((size_t)NE * 8);          // dst-bucketed {e,src}: 6.4 MB
  int2*  cnf     = (int2*)alloc((size_t)NE * 8);
  int2*  cnr     = (int2*)alloc((size_t)NE * 8);
  int*   H       = (int*)alloc((size_t)NBIN * NBLK * 4);  // hist -> row-exclusive prefixes
  int*   rowtot  = (int*)alloc(NBIN * 4);
  int*   sp      = (int*)alloc((NN + 1) * 4);
  int*   rptr    = (int*)alloc((NN + 1) * 4);
  float* dout    = (float*)alloc(NN * 4);
  float* din     = (float*)alloc(NN * 4);
  unsigned short* WT = (unsigned short*)alloc(128 * 160 * 2);

  // zero device-scope atomics, zero memsets, fully parallel scan
  k_aux<<<1058, 256, 0, stream>>>(X, src, dst, ew, H, rptr, dout, Wz, Wh, WT, Xh);
  k_scanrow<<<NBIN, 512, 0, stream>>>(H, rowtot);
  k_part<<<NBLK, 256, 0, stream>>>(src, dst, H, rowtot, cmp64);
  k_fine<<<NBIN, 1024, 0, stream>>>(rowtot, ew, cmp64, cmp, sp, din);
  k_sortw<<<12500, 256, 0, stream>>>(sp, cmp, src, dout, din, cnf, cnr);  // s0+sort+cnf+cnr

  // T1 = P(Xh) both directions, fp16 out only
  k_prop2<<<3125, 256, 0, stream>>>(Xh, sp, cnf, nullptr, T1oh,
                                    Xh, rptr, cnr, nullptr, T1ih, nullptr, 1.f);
  // T2 = 2*P(T1h) - X (fused Chebyshev), fp16 out only
  k_prop2<<<3125, 256, 0, stream>>>(T1oh, sp, cnf, nullptr, T2oh,
                                    T1ih, rptr, cnr, nullptr, T2ih, X, 2.f);

  k_gemm<<<782, 256, 0, stream>>>(Xh, T1oh, T1ih, T2oh, T2ih, WT, bz, bh, out);
}